// Round 10
// baseline (416.070 us; speedup 1.0000x reference)
//
#include <hip/hip_runtime.h>
#include <hip/hip_fp16.h>
#include <math.h>

#define NN 100000
#define NE 3200000
#define FIN 128
#define HD 64
#define TOUT 16
#define BSH 8                        // 256 nodes per bucket
#define NBUK ((NN + 255) / 256)      // 391 buckets
#define EPB 8192                     // edges per P1 block
#define CAP 12288                    // slots per bucket (mean 8192, ~45 sigma headroom)

// ---------------- init bucket cursors to fixed-capacity region starts ----------------
__global__ __launch_bounds__(256) void k_init(int* __restrict__ bcur) {
  int t = blockIdx.x * 256 + threadIdx.x;
  if (t < NBUK) bcur[t] = t * CAP;
}

// ---------------- P1: block-local histogram + contiguous run reservation (fixed-cap buckets) ----------------
__global__ __launch_bounds__(256) void k_p1(const int* __restrict__ src, const int* __restrict__ dst,
                                            int* __restrict__ bcur, unsigned* __restrict__ packed) {
  __shared__ int hist[NBUK];
  __shared__ int base[NBUK];
  int t = threadIdx.x;
  int e0 = blockIdx.x * EPB;
  int e1 = e0 + EPB; if (e1 > NE) e1 = NE;

  for (int i = t; i < NBUK; i += 256) hist[i] = 0;
  __syncthreads();
  for (int e = e0 + t; e < e1; e += 256) atomicAdd(&hist[dst[e] >> BSH], 1);
  __syncthreads();
  for (int i = t; i < NBUK; i += 256) {
    int c = hist[i];
    base[i] = c ? atomicAdd(&bcur[i], c) : 0;
    hist[i] = 0;
  }
  __syncthreads();
  for (int e = e0 + t; e < e1; e += 256) {
    int d = dst[e];
    int b = d >> BSH;
    int p = base[b] + atomicAdd(&hist[b], 1);
    packed[p] = ((unsigned)(d & 255) << 17) | (unsigned)src[e];
  }
}

// ---------------- scan bucket totals -> global bucket bases ----------------
__global__ __launch_bounds__(512) void k_scanb(const int* __restrict__ bcur, int* __restrict__ bktBase,
                                               int* __restrict__ rowptr) {
  __shared__ int s[512];
  int t = threadIdx.x;
  int v = (t < NBUK) ? (bcur[t] - t * CAP) : 0;
  s[t] = v;
  __syncthreads();
  for (int off = 1; off < 512; off <<= 1) {
    int y = (t >= off) ? s[t - off] : 0;
    __syncthreads();
    s[t] += y;
    __syncthreads();
  }
  if (t < NBUK) bktBase[t] = s[t] - v;
  if (t == 0) rowptr[NN] = NE;
}

// ---------------- P2: per-bucket degree histogram + local scan + rowptr/dinv + CSR place ----------------
__global__ __launch_bounds__(256) void k_p2big(const unsigned* __restrict__ packed, const int* __restrict__ bcur,
                                               const int* __restrict__ bktBase, int* __restrict__ rowptr,
                                               float* __restrict__ dinv, int* __restrict__ csr_src) {
  __shared__ int degl[256];
  __shared__ int sc[256];
  __shared__ int cur[256];
  int b = blockIdx.x, t = threadIdx.x;
  int pbase = b * CAP;
  int cnt = bcur[b] - pbase;

  degl[t] = 0;
  __syncthreads();
  for (int i = t; i < cnt; i += 256) {
    unsigned v = packed[pbase + i];
    atomicAdd(&degl[v >> 17], 1);
  }
  __syncthreads();
  int dv = degl[t];
  sc[t] = dv;
  __syncthreads();
  for (int off = 1; off < 256; off <<= 1) {
    int y = (t >= off) ? sc[t - off] : 0;
    __syncthreads();
    sc[t] += y;
    __syncthreads();
  }
  int gpos = bktBase[b] + (sc[t] - dv);
  int node = (b << BSH) + t;
  if (node < NN) {
    rowptr[node] = gpos;
    dinv[node] = 1.0f / sqrtf((float)dv + 1.0f);   // +1 self-loop
  }
  cur[t] = gpos;
  __syncthreads();
  for (int i = t; i < cnt; i += 256) {
    unsigned pv = packed[pbase + i];
    int pos = atomicAdd(&cur[pv >> 17], 1);
    csr_src[pos] = (int)(pv & 0x1FFFFu);
  }
}

// ---------------- tiled GEMM with fp16 scaled output: Ch[n,M] = half((A@W) * scale[r]) ----------------
template<int K>
__global__ __launch_bounds__(256) void k_gemmh(const float* __restrict__ A, const float* __restrict__ W,
                                               __half* __restrict__ Ch, int n, int M,
                                               const float* __restrict__ scale) {
  constexpr int AS = K + 4;
  __shared__ float As[64 * AS];
  int tid = threadIdx.x;
  int rowBase = blockIdx.x * 64;
  int colBase = blockIdx.y * 64;
  int nrows = n - rowBase; if (nrows > 64) nrows = 64;

  for (int idx = tid * 4; idx < 64 * K; idx += 1024) {
    int row = idx / K;
    int k = idx - row * K;
    float4 v = make_float4(0.f, 0.f, 0.f, 0.f);
    if (row < nrows) v = *(const float4*)(A + (size_t)(rowBase + row) * K + k);
    *(float4*)(&As[row * AS + k]) = v;
  }
  __syncthreads();

  int tx = tid & 15, ty = tid >> 4;
  int c0 = colBase + tx * 4;
  int r0 = ty * 4;
  float acc[4][4] = {{0.f}};

  for (int k = 0; k < K; ++k) {
    float4 wv = *(const float4*)(W + (size_t)k * M + c0);
    float wa[4] = {wv.x, wv.y, wv.z, wv.w};
#pragma unroll
    for (int i = 0; i < 4; ++i) {
      float a = As[(r0 + i) * AS + k];
#pragma unroll
      for (int j = 0; j < 4; ++j) acc[i][j] = fmaf(a, wa[j], acc[i][j]);
    }
  }

#pragma unroll
  for (int i = 0; i < 4; ++i) {
    int r = rowBase + r0 + i;
    if (r < n) {
      float sc = scale[r];
      __half2 p0 = __floats2half2_rn(acc[i][0] * sc, acc[i][1] * sc);
      __half2 p1 = __floats2half2_rn(acc[i][2] * sc, acc[i][3] * sc);
      __half2* cp = (__half2*)(Ch + (size_t)r * M + c0);
      cp[0] = p0;
      cp[1] = p1;
    }
  }
}

// ---------------- gather (fp16 table, 4 edges/wave in flight, 8B loads) ----------------
__global__ __launch_bounds__(256) void k_gather(const __half* __restrict__ hws, const int* __restrict__ rowptr,
                                                const int* __restrict__ csr_src, const float* __restrict__ dinv,
                                                const float* __restrict__ b, float* __restrict__ h) {
  int node = blockIdx.x * 4 + (threadIdx.x >> 6);
  if (node >= NN) return;
  int lane = threadIdx.x & 63;
  int f4  = lane & 15;
  int grp = lane >> 4;
  int beg = rowptr[node], end = rowptr[node + 1];
  const uint2* hw2 = (const uint2*)hws;
  float4 acc = make_float4(0.f, 0.f, 0.f, 0.f);

  for (int base = beg; base < end; base += 64) {
    int m = end - base; if (m > 64) m = 64;
    int myS = (lane < m) ? csr_src[base + lane] : 0;
    int nq = m & ~3;
    int i = 0;
#pragma unroll 4
    for (; i < nq; i += 4) {
      int s = __shfl(myS, i + grp);
      uint2 u = hw2[(size_t)s * 16 + f4];
      float2 fa = __half22float2(*(__half2*)&u.x);
      float2 fb = __half22float2(*(__half2*)&u.y);
      acc.x += fa.x; acc.y += fa.y; acc.z += fb.x; acc.w += fb.y;
    }
    if (i < m) {
      int idx = i + grp;
      int s = __shfl(myS, idx < m ? idx : 0);
      if (idx < m) {
        uint2 u = hw2[(size_t)s * 16 + f4];
        float2 fa = __half22float2(*(__half2*)&u.x);
        float2 fb = __half22float2(*(__half2*)&u.y);
        acc.x += fa.x; acc.y += fa.y; acc.z += fb.x; acc.w += fb.y;
      }
    }
  }

  acc.x += __shfl_xor(acc.x, 16); acc.y += __shfl_xor(acc.y, 16);
  acc.z += __shfl_xor(acc.z, 16); acc.w += __shfl_xor(acc.w, 16);
  acc.x += __shfl_xor(acc.x, 32); acc.y += __shfl_xor(acc.y, 32);
  acc.z += __shfl_xor(acc.z, 32); acc.w += __shfl_xor(acc.w, 32);

  if (lane < 16) {
    uint2 u = hw2[(size_t)node * 16 + f4];
    float2 fa = __half22float2(*(__half2*)&u.x);
    float2 fb = __half22float2(*(__half2*)&u.y);
    acc.x += fa.x; acc.y += fa.y; acc.z += fb.x; acc.w += fb.y;
    float di = dinv[node];
    float4 bb = ((const float4*)b)[f4];
    float4 o;
    o.x = fmaxf(fmaf(di, acc.x, bb.x), 0.f);
    o.y = fmaxf(fmaf(di, acc.y, bb.y), 0.f);
    o.z = fmaxf(fmaf(di, acc.z, bb.z), 0.f);
    o.w = fmaxf(fmaf(di, acc.w, bb.w), 0.f);
    *(float4*)(h + (size_t)node * HD + f4 * 4) = o;
  }
}

// ---------------- prep: Wcat[k][192] = k<64 ? w_ih[:,k].T : w_hh[:,k-64].T ----------------
__global__ __launch_bounds__(256) void k_prep(const float* __restrict__ w_ih, const float* __restrict__ w_hh,
                                              float* __restrict__ Wcat) {
  int t = blockIdx.x * 256 + threadIdx.x;
  if (t >= 128 * 192) return;
  int k = t / 192, c = t - k * 192;
  Wcat[t] = (k < 64) ? w_ih[c * 64 + k] : w_hh[c * 64 + (k - 64)];
}

// ---------------- fused GRU v3: scalar(SGPR) weight stream, lane=row, wave=16 cols ----------------
// A-tile k-major: As2[k][64] (h in k=0..63, h0 in k=64..127), 32KB LDS.
// Per kk per wave: 1 conflict-free ds_read_b32 + 48 FMA; weights via wave-uniform s_load.
__global__ __launch_bounds__(256) void k_grufused(const float* __restrict__ h, const float* __restrict__ prev,
                                                  const float* __restrict__ Wcat,
                                                  const float* __restrict__ bih, const float* __restrict__ bhh,
                                                  const float* __restrict__ Wp, const float* __restrict__ bp,
                                                  float* __restrict__ hnew, float* __restrict__ out) {
  __shared__ float As2[128 * 64];   // 32,768 B
  int tid = threadIdx.x;
  int rowBase = blockIdx.x * 64;
  int nrows = NN - rowBase; if (nrows > 64) nrows = 64;
  int row = tid & 63;               // lane = row
  int c4base = tid >> 6;            // 0..3

  // stage k-major: h -> k 0..63, prev -> k 64..127 (zero-fill OOB rows)
  for (int c4 = c4base; c4 < 32; c4 += 4) {
    float4 v = make_float4(0.f, 0.f, 0.f, 0.f);
    if (row < nrows) {
      if (c4 < 16) v = *(const float4*)(h + (size_t)(rowBase + row) * HD + c4 * 4);
      else         v = *(const float4*)(prev + (size_t)(rowBase + row) * HD + (c4 - 16) * 4);
    }
    int k0 = c4 * 4;
    As2[(k0 + 0) * 64 + row] = v.x;
    As2[(k0 + 1) * 64 + row] = v.y;
    As2[(k0 + 2) * 64 + row] = v.z;
    As2[(k0 + 3) * 64 + row] = v.w;
  }
  __syncthreads();

  int wid = __builtin_amdgcn_readfirstlane(tid >> 6);   // force wave-uniform
  int cbase = wid * 16;                                 // this wave's 16 output cols

  float aR[16] = {0.f}, aZ[16] = {0.f}, aNi[16] = {0.f}, aNh[16] = {0.f};

  // phase 1: k<64 (A = h); n-gate -> aNi
#pragma unroll 2
  for (int kk = 0; kk < 64; ++kk) {
    float a = As2[kk * 64 + row];
    const float* Wk = Wcat + kk * 192 + cbase;          // wave-uniform address -> s_load
#pragma unroll
    for (int j = 0; j < 16; ++j) {
      aR[j]  = fmaf(a, Wk[j], aR[j]);
      aZ[j]  = fmaf(a, Wk[64 + j], aZ[j]);
      aNi[j] = fmaf(a, Wk[128 + j], aNi[j]);
    }
  }
  // phase 2: k>=64 (A = h0); n-gate -> aNh
#pragma unroll 2
  for (int kk = 64; kk < 128; ++kk) {
    float a = As2[kk * 64 + row];
    const float* Wk = Wcat + kk * 192 + cbase;
#pragma unroll
    for (int j = 0; j < 16; ++j) {
      aR[j]  = fmaf(a, Wk[j], aR[j]);
      aZ[j]  = fmaf(a, Wk[64 + j], aZ[j]);
      aNh[j] = fmaf(a, Wk[128 + j], aNh[j]);
    }
  }

  // epilogue: gates + hnew (all lane-local; h0 from LDS)
  float hn[16];
#pragma unroll
  for (int j = 0; j < 16; ++j) {
    float h0v = As2[(64 + cbase + j) * 64 + row];
    float rg = 1.f / (1.f + expf(-(aR[j] + bih[cbase + j] + bhh[cbase + j])));
    float zg = 1.f / (1.f + expf(-(aZ[j] + bih[64 + cbase + j] + bhh[64 + cbase + j])));
    float nc = tanhf(aNi[j] + bih[128 + cbase + j] + rg * (aNh[j] + bhh[128 + cbase + j]));
    hn[j] = (1.f - zg) * nc + zg * h0v;
  }
  if (row < nrows) {
#pragma unroll
    for (int j4 = 0; j4 < 4; ++j4)
      *(float4*)(hnew + (size_t)(rowBase + row) * HD + cbase + j4 * 4) =
          make_float4(hn[j4 * 4], hn[j4 * 4 + 1], hn[j4 * 4 + 2], hn[j4 * 4 + 3]);
  }

  // readout partials: pt[t] = sum_j hn[j] * Wp[cbase+j][t]  (Wp rows wave-uniform -> s_load)
  float pt[16] = {0.f};
#pragma unroll
  for (int j = 0; j < 16; ++j) {
    const float* wp = Wp + (size_t)(cbase + j) * TOUT;
#pragma unroll
    for (int t = 0; t < 16; ++t) pt[t] = fmaf(hn[j], wp[t], pt[t]);
  }

  __syncthreads();                  // As2 fully consumed; reuse as exchange buffer
  float* ex = As2;                  // part[w][row][t], stride 17 (bank-spread)
#pragma unroll
  for (int t = 0; t < 16; ++t) ex[wid * 1088 + row * 17 + t] = pt[t];
  __syncthreads();

  int orow = tid >> 2;
  int t4 = (tid & 3) * 4;
  if (rowBase + orow < NN) {
    float4 bb = *(const float4*)(bp + t4);
    float s0 = bb.x, s1 = bb.y, s2 = bb.z, s3 = bb.w;
#pragma unroll
    for (int w = 0; w < 4; ++w) {
      s0 += ex[w * 1088 + orow * 17 + t4 + 0];
      s1 += ex[w * 1088 + orow * 17 + t4 + 1];
      s2 += ex[w * 1088 + orow * 17 + t4 + 2];
      s3 += ex[w * 1088 + orow * 17 + t4 + 3];
    }
    *(float4*)(out + (size_t)(rowBase + orow) * TOUT + t4) = make_float4(s0, s1, s2, s3);
  }
}

extern "C" void kernel_launch(void* const* d_in, const int* in_sizes, int n_in,
                              void* d_out, int out_size, void* d_ws, size_t ws_size,
                              hipStream_t stream) {
  const float* x    = (const float*)d_in[0];
  const int*   ei   = (const int*)d_in[1];
  const float* prev = (const float*)d_in[2];
  const float* W1   = (const float*)d_in[3];
  const float* b1   = (const float*)d_in[4];
  const float* W2   = (const float*)d_in[5];
  const float* b2   = (const float*)d_in[6];
  const float* w_ih = (const float*)d_in[7];
  const float* w_hh = (const float*)d_in[8];
  const float* b_ih = (const float*)d_in[9];
  const float* b_hh = (const float*)d_in[10];
  const float* Wp   = (const float*)d_in[11];
  const float* bp   = (const float*)d_in[12];

  float* out  = (float*)d_out;                 // [NN,16]
  float* hnew = out + (size_t)NN * TOUT;       // [NN,64]

  char* ws = (char*)d_ws;
  float*    dinv    = (float*)(ws + 0);                    // 400,000
  int*      rowptr  = (int*)(ws + 400000);                 // 400,064
  int*      bcur    = (int*)(ws + 800064);                 // 1,564
  int*      bktBase = (int*)(ws + 801664);                 // 1,564
  int*      csr_src = (int*)(ws + 803264);                 // 12,800,000
  __half*   hwsH    = (__half*)(ws + 13603264);            // 12,800,000
  float*    bufB    = (float*)(ws + 26403264);             // 25,600,000 (packed u32 alias; CAP*NBUK*4 = 19.2MB)
  float*    bufC    = (float*)(ws + 52003264);             // 25,600,000
  float*    Wcat    = (float*)(ws + 77603264);             // 98,304
  unsigned* packed  = (unsigned*)bufB;

  const int* srcA = ei;
  const int* dstA = ei + NE;

  // ---- CSR build (no degree pre-pass) ----
  k_init<<<(NBUK + 255) / 256, 256, 0, stream>>>(bcur);
  k_p1<<<(NE + EPB - 1) / EPB, 256, 0, stream>>>(srcA, dstA, bcur, packed);
  k_scanb<<<1, 512, 0, stream>>>(bcur, bktBase, rowptr);
  k_p2big<<<NBUK, 256, 0, stream>>>(packed, bcur, bktBase, rowptr, dinv, csr_src);

  // ---- GCN layer 1 ----
  k_gemmh<FIN><<<dim3((NN + 63) / 64, 1), 256, 0, stream>>>(x, W1, hwsH, NN, HD, dinv);
  k_gather<<<(NN + 3) / 4, 256, 0, stream>>>(hwsH, rowptr, csr_src, dinv, b1, bufC);

  // ---- GCN layer 2 ----
  k_gemmh<HD><<<dim3((NN + 63) / 64, 1), 256, 0, stream>>>(bufC, W2, hwsH, NN, HD, dinv);
  k_gather<<<(NN + 3) / 4, 256, 0, stream>>>(hwsH, rowptr, csr_src, dinv, b2, bufC);

  // ---- fused GRU (scalar-weight K=128 GEMM + gates + readout) ----
  k_prep<<<(128 * 192 + 255) / 256, 256, 0, stream>>>(w_ih, w_hh, Wcat);
  k_grufused<<<(NN + 63) / 64, 256, 0, stream>>>(bufC, prev, Wcat, b_ih, b_hh, Wp, bp, hnew, out);
}